// Round 6
// baseline (352.021 us; speedup 1.0000x reference)
//
#include <hip/hip_runtime.h>

#define DDIM 256
#define NEDGE 4096
#define SLEN 64
#define NNODE 1024
#define ROWS 65536

typedef short s16x8 __attribute__((ext_vector_type(8)));
typedef float f32x4 __attribute__((ext_vector_type(4)));

static __device__ __forceinline__ unsigned short f2bf(float f){
  union { float f; unsigned u; } v; v.f = f;
  unsigned r = v.u + 0x7FFFu + ((v.u >> 16) & 1u);
  return (unsigned short)(r >> 16);
}

static __device__ __forceinline__ void gl2lds16(const unsigned short* g, unsigned short* l){
  __builtin_amdgcn_global_load_lds((const __attribute__((address_space(1))) unsigned int*)g,
                                   (__attribute__((address_space(3))) unsigned int*)l, 16, 0, 0);
}

// ---------------- setup: LN + weight prep + lengths + degrees, fused ----------------
__global__ __launch_bounds__(256) void setup_kernel(const float* nf, const float* lnw, const float* lnb,
                                                    const float* wq, const float* wk, const float* wv, const float* wo,
                                                    const float* bq, const float* bk, const float* bv,
                                                    const float* masks, const int* eidx,
                                                    unsigned short* xn, unsigned short* Wqkv, unsigned short* Wo_t,
                                                    float* qkvb, int* lenp, int* deg){
  int bid = blockIdx.x, tid = threadIdx.x;
  if (bid < 16384){
    int lane = tid & 63;
    int row = bid*4 + (tid >> 6);
    const float4 x4 = ((const float4*)(nf + (size_t)row*DDIM))[lane];
    float s  = x4.x + x4.y + x4.z + x4.w;
    float sq = x4.x*x4.x + x4.y*x4.y + x4.z*x4.z + x4.w*x4.w;
    for (int off=1; off<64; off<<=1){ s += __shfl_xor(s, off); sq += __shfl_xor(sq, off); }
    float mu  = s  * (1.0f/DDIM);
    float var = sq * (1.0f/DDIM) - mu*mu;
    float rs  = rsqrtf(var + 1e-5f);
    float4 w4 = ((const float4*)lnw)[lane];
    float4 b4 = ((const float4*)lnb)[lane];
    ushort4 o;
    o.x = f2bf((x4.x - mu)*rs*w4.x + b4.x);
    o.y = f2bf((x4.y - mu)*rs*w4.y + b4.y);
    o.z = f2bf((x4.z - mu)*rs*w4.z + b4.z);
    o.w = f2bf((x4.w - mu)*rs*w4.w + b4.w);
    ((ushort4*)(xn + (size_t)row*DDIM))[lane] = o;
  } else if (bid < 17412){
    int idx = (bid - 16384)*256 + tid;
    if (idx < 196608){
      int mat = idx >> 16;
      int rem = idx & 65535;
      int n = rem >> 8, k = rem & 255;
      const float* W = (mat==0)?wq:(mat==1)?wk:wv;
      Wqkv[(size_t)(mat*256 + n)*256 + k] = f2bf(W[k*256 + n]);
    } else if (idx < 262144){
      int rem = idx - 196608;
      int n = rem >> 8, k = rem & 255;
      Wo_t[(size_t)n*256 + k] = f2bf(wo[k*256 + n]);
    } else if (idx < 262912){
      int i = idx - 262144;
      qkvb[i] = (i < 256) ? bq[i] : (i < 512) ? bk[i-256] : bv[i-512];
    }
  } else if (bid < 17668){
    int lane = tid & 63;
    int node = (bid - 17412)*4 + (tid >> 6);
    unsigned long long b = __ballot(masks[node*SLEN + lane] > 0.f);
    if (lane == 0) lenp[node] = __popcll(b);
  } else {
    int e = (bid - 17668)*256 + tid;
    if (e < NEDGE) atomicAdd(&deg[eidx[e]], 1);
  }
}

__global__ void scan_kernel(const int* deg, int* startp, int* order){
  __shared__ int buf[NNODE];
  __shared__ int hist[65];
  int t = threadIdx.x;
  int d = deg[t];
  buf[t] = d;
  if (t < 65) hist[t] = 0;
  __syncthreads();
  for (int off=1; off<NNODE; off<<=1){
    int v = (t >= off) ? buf[t-off] : 0;
    __syncthreads();
    buf[t] += v;
    __syncthreads();
  }
  startp[t] = buf[t] - d;
  int dc = d > 64 ? 64 : d;
  atomicAdd(&hist[dc], 1);
  __syncthreads();
  if (t == 0){
    int acc = 0;
    for (int i = 64; i >= 0; i--){ int h = hist[i]; hist[i] = acc; acc += h; }
  }
  __syncthreads();
  int pos = atomicAdd(&hist[dc], 1);
  order[pos] = t;
}

__global__ __launch_bounds__(256) void edge_fill_kernel(const int* eidx, const int* startp, int* cursor, int* elist){
  int e = blockIdx.x*256 + threadIdx.x;
  if (e < NEDGE){
    int s = eidx[e];
    int p = atomicAdd(&cursor[s], 1);
    elist[startp[s] + p] = eidx[NEDGE + e];
  }
}

// ---------------- QKV GEMM: M=65536 N=768 K=256; 64x128 tile; V written transposed ----------------
__global__ __launch_bounds__(256) void qkv_kernel(const unsigned short* xn, const unsigned short* Wqkv,
                                                  const float* qkvb,
                                                  unsigned short* qb, unsigned short* kb_, unsigned short* vt){
  __shared__ __align__(16) unsigned short As[4096];
  __shared__ __align__(16) unsigned short Bs[8192];
  int tid = threadIdx.x;
  int lane = tid & 63, wid = tid >> 6, m = lane & 15, quad = lane >> 4;
  int row0 = blockIdx.x * 64;
  int col0 = blockIdx.y * 128;
  int rw = (wid & 1) * 32, cw = (wid >> 1) * 64;
  f32x4 acc[8];
  #pragma unroll
  for (int i=0;i<8;i++) acc[i] = (f32x4){0.f,0.f,0.f,0.f};
  for (int kc = 0; kc < 4; kc++){
    __syncthreads();
    #pragma unroll
    for (int i=0;i<2;i++){
      int cid = i*256 + tid, row = cid >> 3, c8 = cid & 7;
      gl2lds16(xn + (size_t)(row0 + row)*DDIM + kc*64 + ((c8 ^ (row&7))<<3), As + cid*8);
    }
    #pragma unroll
    for (int i=0;i<4;i++){
      int cid = i*256 + tid, row = cid >> 3, c8 = cid & 7;
      gl2lds16(Wqkv + (size_t)(col0 + row)*DDIM + kc*64 + ((c8 ^ (row&7))<<3), Bs + cid*8);
    }
    __syncthreads();
    #pragma unroll
    for (int ks=0; ks<2; ks++){
      int sw = ((ks*4 + quad) ^ (m&7)) << 3;
      s16x8 af[2], bf[4];
      #pragma unroll
      for (int mt=0;mt<2;mt++) af[mt] = *(const s16x8*)(As + (rw + mt*16 + m)*64 + sw);
      #pragma unroll
      for (int nt=0;nt<4;nt++) bf[nt] = *(const s16x8*)(Bs + (cw + nt*16 + m)*64 + sw);
      #pragma unroll
      for (int mt=0;mt<2;mt++)
        #pragma unroll
        for (int nt=0;nt<4;nt++)
          acc[mt*4+nt] = __builtin_amdgcn_mfma_f32_16x16x32_bf16(af[mt], bf[nt], acc[mt*4+nt], 0,0,0);
    }
  }
  int node = row0 >> 6;   // 64-row tile == one node
  #pragma unroll
  for (int nt=0;nt<4;nt++){
    int cg = col0 + cw + nt*16 + m;
    int mat = cg >> 8, col = cg & 255;
    float bb = qkvb[cg];
    if (mat < 2){
      unsigned short* ob = (mat==0)?qb:kb_;
      #pragma unroll
      for (int mt=0;mt<2;mt++)
        #pragma unroll
        for (int r=0;r<4;r++){
          int row = row0 + rw + mt*16 + quad*4 + r;
          ob[(size_t)row*DDIM + col] = f2bf(acc[mt*4+nt][r] + bb);
        }
    } else {
      // V: transposed store vt[node][col][token], 4 consecutive tokens -> one 8B store
      #pragma unroll
      for (int mt=0;mt<2;mt++){
        int tok0 = rw + mt*16 + quad*4;
        ushort4 p;
        p.x = f2bf(acc[mt*4+nt][0] + bb);
        p.y = f2bf(acc[mt*4+nt][1] + bb);
        p.z = f2bf(acc[mt*4+nt][2] + bb);
        p.w = f2bf(acc[mt*4+nt][3] + bb);
        *(ushort4*)(vt + ((size_t)node*256 + col)*64 + tok0) = p;
      }
    }
  }
}

// ---------------- attention: block=(src,head), 4 waves=q-tiles, all-async dbuf staging ----------------
__global__ __launch_bounds__(256) void attn_kernel(const unsigned short* qb, const unsigned short* kbuf,
                                                   const unsigned short* vtb, const int* lenp,
                                                   const int* startp, const int* degp, const int* elist,
                                                   const int* order, unsigned short* ctxb){
  __shared__ __align__(16) unsigned short Kt[2][4096];  // [key 64][d 64], chunk-swizzled
  __shared__ __align__(16) unsigned short Vt[2][4096];  // [d 64][token 64], chunk-swizzled
  __shared__ unsigned short P[4096];                    // per wave 1024: [q 16][key 64], swizzled
  int tid = threadIdx.x;
  int lane = tid & 63, wid = tid >> 6, m = lane & 15, quad = lane >> 4;
  int src = order[blockIdx.x], h = blockIdx.y;
  int ls = lenp[src];
  int qtm = (ls + 15) >> 4;
  int s0 = startp[src], dg = degp[src];
  bool active = wid < qtm;
  unsigned short* Pw = P + wid*1024;

  s16x8 qf0 = {0,0,0,0,0,0,0,0}, qf1 = {0,0,0,0,0,0,0,0};
  if (active){
    const unsigned short* qbase = qb + (size_t)(src*SLEN + wid*16 + m)*DDIM + h*64 + quad*8;
    qf0 = *(const s16x8*)(qbase);
    qf1 = *(const s16x8*)(qbase + 32);
  }
  f32x4 o[4];
  #pragma unroll
  for (int i=0;i<4;i++) o[i] = (f32x4){0.f,0.f,0.f,0.f};

  int dst0 = 0, dst1 = 0, ld0 = 0;
  if (dg > 0){
    dst0 = elist[s0];
    ld0 = lenp[dst0];
    int kch = ((ld0 + 15) >> 4) * 128;   // K chunks needed (16B units), multiple of 128
    #pragma unroll
    for (int i=0;i<2;i++){
      int cid = i*256 + tid;
      if (i*256 + wid*64 < kch){
        int row = cid >> 3, c8 = cid & 7;
        gl2lds16(kbuf + (size_t)(dst0*SLEN + row)*DDIM + h*64 + ((c8 ^ (row&7))<<3), Kt[0] + cid*8);
      }
    }
    const unsigned short* vhead = vtb + ((size_t)dst0*256 + h*64)*64;
    #pragma unroll
    for (int i=0;i<2;i++){
      int cid = i*256 + tid, row = cid >> 3, c8 = cid & 7;
      gl2lds16(vhead + row*64 + ((c8 ^ (row&7))<<3), Vt[0] + cid*8);
    }
  }
  if (dg > 1) dst1 = elist[s0 + 1];
  __syncthreads();

  for (int ei=0; ei<dg; ei++){
    int cur = ei & 1, nxt = cur ^ 1;
    int dst2 = (ei+2 < dg) ? elist[s0 + ei + 2] : 0;   // 2-deep prefetch
    int ld1 = 0;
    if (ei+1 < dg){
      ld1 = lenp[dst1];
      int kch = ((ld1 + 15) >> 4) * 128;
      #pragma unroll
      for (int i=0;i<2;i++){
        int cid = i*256 + tid;
        if (i*256 + wid*64 < kch){
          int row = cid >> 3, c8 = cid & 7;
          gl2lds16(kbuf + (size_t)(dst1*SLEN + row)*DDIM + h*64 + ((c8 ^ (row&7))<<3), Kt[nxt] + cid*8);
        }
      }
      const unsigned short* vhead = vtb + ((size_t)dst1*256 + h*64)*64;
      #pragma unroll
      for (int i=0;i<2;i++){
        int cid = i*256 + tid, row = cid >> 3, c8 = cid & 7;
        gl2lds16(vhead + row*64 + ((c8 ^ (row&7))<<3), Vt[nxt] + cid*8);
      }
    }
    int ktm = (ld0 + 15) >> 4;
    int ks2 = (ktm + 1) >> 1;
    if (active){
      f32x4 acc[4];
      #pragma unroll
      for (int i=0;i<4;i++) acc[i] = (f32x4){0.f,0.f,0.f,0.f};
      #pragma unroll
      for (int kt=0; kt<4; kt++) if (kt < ktm){
        int key = kt*16 + m;
        s16x8 b0 = *(const s16x8*)(Kt[cur] + key*64 + ((quad ^ (m&7))<<3));
        acc[kt] = __builtin_amdgcn_mfma_f32_16x16x32_bf16(qf0, b0, acc[kt], 0,0,0);
        s16x8 b1 = *(const s16x8*)(Kt[cur] + key*64 + (((4 + quad) ^ (m&7))<<3));
        acc[kt] = __builtin_amdgcn_mfma_f32_16x16x32_bf16(qf1, b1, acc[kt], 0,0,0);
      }
      // softmax (no max-subtraction: |score/8| small; shift-invariant math)
      #pragma unroll
      for (int r=0; r<4; r++){
        float x[4];
        #pragma unroll
        for (int kt=0; kt<4; kt++)
          x[kt] = (kt < ktm && kt*16 + m < ld0) ? __expf(acc[kt][r]*0.125f) : 0.f;
        float s = x[0] + x[1] + x[2] + x[3];
        for (int off=1; off<16; off<<=1) s += __shfl_xor(s, off);
        float inv = 1.0f / s;
        int q = quad*4 + r;
        #pragma unroll
        for (int kt=0; kt<4; kt++) if (kt < 2*ks2){
          int key = kt*16 + m;
          Pw[q*64 + (((key>>3)^(q&7))<<3) + (key&7)] = f2bf(x[kt]*inv);
        }
      }
      #pragma unroll
      for (int ks=0; ks<2; ks++) if (ks < ks2){
        s16x8 pa = *(const s16x8*)(Pw + m*64 + ((((ks*4+quad))^(m&7))<<3));
        #pragma unroll
        for (int dt=0; dt<4; dt++){
          int d = dt*16 + m;
          s16x8 vf = *(const s16x8*)(Vt[cur] + d*64 + (((ks*4+quad)^(d&7))<<3));
          o[dt] = __builtin_amdgcn_mfma_f32_16x16x32_bf16(pa, vf, o[dt], 0,0,0);
        }
      }
    }
    dst0 = dst1; ld0 = ld1; dst1 = dst2;
    __syncthreads();
  }
  if (active){
    #pragma unroll
    for (int dt=0; dt<4; dt++){
      int col = h*64 + dt*16 + m;
      #pragma unroll
      for (int r=0; r<4; r++){
        int row = src*SLEN + wid*16 + quad*4 + r;
        ctxb[(size_t)row*DDIM + col] = f2bf(o[dt][r]);
      }
    }
  }
}

// ---------------- output GEMM: M=65536 N=256 K=256, 64x128 tile + bias/residual/mask ----------------
__global__ __launch_bounds__(256) void out_kernel(const unsigned short* ctxb, const unsigned short* Wo_t,
                                                  const float* bo, const float* nf, const float* masks,
                                                  float* out){
  __shared__ __align__(16) unsigned short As[4096];
  __shared__ __align__(16) unsigned short Bs[8192];
  int tid = threadIdx.x;
  int lane = tid & 63, wid = tid >> 6, m = lane & 15, quad = lane >> 4;
  int row0 = blockIdx.x * 64;
  int col0 = blockIdx.y * 128;
  int rw = (wid & 1) * 32, cw = (wid >> 1) * 64;
  f32x4 acc[8];
  #pragma unroll
  for (int i=0;i<8;i++) acc[i] = (f32x4){0.f,0.f,0.f,0.f};
  for (int kc = 0; kc < 4; kc++){
    __syncthreads();
    #pragma unroll
    for (int i=0;i<2;i++){
      int cid = i*256 + tid, row = cid >> 3, c8 = cid & 7;
      gl2lds16(ctxb + (size_t)(row0 + row)*DDIM + kc*64 + ((c8 ^ (row&7))<<3), As + cid*8);
    }
    #pragma unroll
    for (int i=0;i<4;i++){
      int cid = i*256 + tid, row = cid >> 3, c8 = cid & 7;
      gl2lds16(Wo_t + (size_t)(col0 + row)*DDIM + kc*64 + ((c8 ^ (row&7))<<3), Bs + cid*8);
    }
    __syncthreads();
    #pragma unroll
    for (int ks=0; ks<2; ks++){
      int sw = ((ks*4 + quad) ^ (m&7)) << 3;
      s16x8 af[2], bf[4];
      #pragma unroll
      for (int mt=0;mt<2;mt++) af[mt] = *(const s16x8*)(As + (rw + mt*16 + m)*64 + sw);
      #pragma unroll
      for (int nt=0;nt<4;nt++) bf[nt] = *(const s16x8*)(Bs + (cw + nt*16 + m)*64 + sw);
      #pragma unroll
      for (int mt=0;mt<2;mt++)
        #pragma unroll
        for (int nt=0;nt<4;nt++)
          acc[mt*4+nt] = __builtin_amdgcn_mfma_f32_16x16x32_bf16(af[mt], bf[nt], acc[mt*4+nt], 0,0,0);
    }
  }
  #pragma unroll
  for (int nt=0;nt<4;nt++){
    int col = col0 + cw + nt*16 + m;
    float bb = bo[col];
    #pragma unroll
    for (int mt=0;mt<2;mt++)
      #pragma unroll
      for (int r=0;r<4;r++){
        int row = row0 + rw + mt*16 + quad*4 + r;
        float v = acc[mt*4+nt][r] + bb + nf[(size_t)row*DDIM + col];
        out[(size_t)row*DDIM + col] = v * masks[row];
      }
  }
}

extern "C" void kernel_launch(void* const* d_in, const int* in_sizes, int n_in,
                              void* d_out, int out_size, void* d_ws, size_t ws_size,
                              hipStream_t stream){
  const float* nf    = (const float*)d_in[0];
  const float* masks = (const float*)d_in[1];
  const float* lnw   = (const float*)d_in[2];
  const float* lnb   = (const float*)d_in[3];
  const float* wq    = (const float*)d_in[4];
  const float* bq    = (const float*)d_in[5];
  const float* wk    = (const float*)d_in[6];
  const float* bk    = (const float*)d_in[7];
  const float* wv    = (const float*)d_in[8];
  const float* bv    = (const float*)d_in[9];
  const float* wo    = (const float*)d_in[10];
  const float* bo    = (const float*)d_in[11];
  const int*   eidx  = (const int*)d_in[13];
  float* out = (float*)d_out;

  char* ws = (char*)d_ws;
  const size_t B = (size_t)ROWS * DDIM * 2;
  unsigned short* xn   = (unsigned short*)(ws);
  unsigned short* qb   = (unsigned short*)(ws + B);
  unsigned short* kb   = (unsigned short*)(ws + 2*B);
  unsigned short* vt   = (unsigned short*)(ws + 3*B);   // V transposed: [node][col 256][token 64]
  unsigned short* ctxb = (unsigned short*)(ws + 4*B);
  char* wp = ws + 5*B;
  unsigned short* Wqkv = (unsigned short*)(wp);
  unsigned short* Wo_t = (unsigned short*)(wp + 393216);
  float* qkvb         = (float*)(wp + 524288);
  char* ip = wp + 528384;
  int* deg    = (int*)(ip);
  int* cursor = (int*)(ip + 4096);
  int* startp = (int*)(ip + 8192);
  int* lenp   = (int*)(ip + 12288);
  int* order  = (int*)(ip + 16384);
  int* elist  = (int*)(ip + 20480);

  hipMemsetAsync(deg, 0, 8192, stream);   // deg + cursor
  setup_kernel<<<17684, 256, 0, stream>>>(nf, lnw, lnb, wq, wk, wv, wo, bq, bk, bv,
                                          masks, eidx, xn, Wqkv, Wo_t, qkvb, lenp, deg);
  scan_kernel<<<1, NNODE, 0, stream>>>(deg, startp, order);
  edge_fill_kernel<<<NEDGE/256, 256, 0, stream>>>(eidx, startp, cursor, elist);
  qkv_kernel<<<dim3(ROWS/64, 6), 256, 0, stream>>>(xn, Wqkv, qkvb, qb, kb, vt);
  attn_kernel<<<dim3(NNODE, 4), 256, 0, stream>>>(qb, kb, vt, lenp, startp, deg, elist, order, ctxb);
  out_kernel<<<dim3(ROWS/64, 2), 256, 0, stream>>>(ctxb, Wo_t, bo, nf, masks, out);
}

// Round 7
// 345.748 us; speedup vs baseline: 1.0181x; 1.0181x over previous
//
#include <hip/hip_runtime.h>

#define DDIM 256
#define NEDGE 4096
#define SLEN 64
#define NNODE 1024
#define ROWS 65536

typedef short s16x8 __attribute__((ext_vector_type(8)));
typedef float f32x4 __attribute__((ext_vector_type(4)));

static __device__ __forceinline__ unsigned short f2bf(float f){
  union { float f; unsigned u; } v; v.f = f;
  unsigned r = v.u + 0x7FFFu + ((v.u >> 16) & 1u);
  return (unsigned short)(r >> 16);
}

static __device__ __forceinline__ void gl2lds16(const unsigned short* g, unsigned short* l){
  __builtin_amdgcn_global_load_lds((const __attribute__((address_space(1))) unsigned int*)g,
                                   (__attribute__((address_space(3))) unsigned int*)l, 16, 0, 0);
}

// ---------------- setup: LN + weight prep + lengths, fused ----------------
__global__ __launch_bounds__(256) void setup_kernel(const float* nf, const float* lnw, const float* lnb,
                                                    const float* wq, const float* wk, const float* wv, const float* wo,
                                                    const float* bq, const float* bk, const float* bv,
                                                    const float* masks,
                                                    unsigned short* xn, unsigned short* Wqkv, unsigned short* Wo_t,
                                                    float* qkvb, int* lenp){
  int bid = blockIdx.x, tid = threadIdx.x;
  if (bid < 16384){
    int lane = tid & 63;
    int row = bid*4 + (tid >> 6);
    const float4 x4 = ((const float4*)(nf + (size_t)row*DDIM))[lane];
    float s  = x4.x + x4.y + x4.z + x4.w;
    float sq = x4.x*x4.x + x4.y*x4.y + x4.z*x4.z + x4.w*x4.w;
    for (int off=1; off<64; off<<=1){ s += __shfl_xor(s, off); sq += __shfl_xor(sq, off); }
    float mu  = s  * (1.0f/DDIM);
    float var = sq * (1.0f/DDIM) - mu*mu;
    float rs  = rsqrtf(var + 1e-5f);
    float4 w4 = ((const float4*)lnw)[lane];
    float4 b4 = ((const float4*)lnb)[lane];
    ushort4 o;
    o.x = f2bf((x4.x - mu)*rs*w4.x + b4.x);
    o.y = f2bf((x4.y - mu)*rs*w4.y + b4.y);
    o.z = f2bf((x4.z - mu)*rs*w4.z + b4.z);
    o.w = f2bf((x4.w - mu)*rs*w4.w + b4.w);
    ((ushort4*)(xn + (size_t)row*DDIM))[lane] = o;
  } else if (bid < 17412){
    int idx = (bid - 16384)*256 + tid;
    if (idx < 196608){
      int mat = idx >> 16;
      int rem = idx & 65535;
      int n = rem >> 8, k = rem & 255;
      const float* W = (mat==0)?wq:(mat==1)?wk:wv;
      Wqkv[(size_t)(mat*256 + n)*256 + k] = f2bf(W[k*256 + n]);
    } else if (idx < 262144){
      int rem = idx - 196608;
      int n = rem >> 8, k = rem & 255;
      Wo_t[(size_t)n*256 + k] = f2bf(wo[k*256 + n]);
    } else if (idx < 262912){
      int i = idx - 262144;
      qkvb[i] = (i < 256) ? bq[i] : (i < 512) ? bk[i-256] : bv[i-512];
    }
  } else {
    int lane = tid & 63;
    int node = (bid - 17412)*4 + (tid >> 6);
    unsigned long long b = __ballot(masks[node*SLEN + lane] > 0.f);
    if (lane == 0) lenp[node] = __popcll(b);
  }
}

// ---------------- CSR: degree + scan + degree-sort + fill, one block ----------------
__global__ void csr_kernel(const int* eidx, int* startp, int* order, int* degp, int* elist){
  __shared__ int deg[NNODE];
  __shared__ int buf[NNODE];
  __shared__ int hist[65];
  __shared__ int cur[NNODE];
  int t = threadIdx.x;
  deg[t] = 0;
  if (t < 65) hist[t] = 0;
  __syncthreads();
  #pragma unroll
  for (int i=0;i<4;i++) atomicAdd(&deg[eidx[i*1024 + t]], 1);
  __syncthreads();
  int d = deg[t];
  buf[t] = d;
  __syncthreads();
  for (int off=1; off<NNODE; off<<=1){
    int v = (t >= off) ? buf[t-off] : 0;
    __syncthreads();
    buf[t] += v;
    __syncthreads();
  }
  int st = buf[t] - d;
  startp[t] = st; degp[t] = d; cur[t] = st;
  int dc = d > 64 ? 64 : d;
  atomicAdd(&hist[dc], 1);
  __syncthreads();
  if (t == 0){
    int acc = 0;
    for (int i=64;i>=0;i--){ int h = hist[i]; hist[i] = acc; acc += h; }
  }
  __syncthreads();
  int pos = atomicAdd(&hist[dc], 1);
  order[pos] = t;
  __syncthreads();
  #pragma unroll
  for (int i=0;i<4;i++){
    int e = i*1024 + t;
    int s = eidx[e];
    int p = atomicAdd(&cur[s], 1);
    elist[p] = eidx[NEDGE + e];
  }
}

// ---------------- QKV GEMM, mask-aware row-tile skipping; V written transposed ----------------
__global__ __launch_bounds__(256) void qkv_kernel(const unsigned short* xn, const unsigned short* Wqkv,
                                                  const float* qkvb, const int* lenp,
                                                  unsigned short* qb, unsigned short* kb_, unsigned short* vt){
  __shared__ __align__(16) unsigned short As[4096];
  __shared__ __align__(16) unsigned short Bs[8192];
  int tid = threadIdx.x;
  int lane = tid & 63, wid = tid >> 6, m = lane & 15, quad = lane >> 4;
  int row0 = blockIdx.x * 64;
  int node = row0 >> 6;
  int qtm = (lenp[node] + 15) >> 4;     // valid row tiles (1..4)
  int vrows = qtm << 4;
  int col0 = blockIdx.y * 128;
  int rw = (wid & 1) * 32, cw = (wid >> 1) * 64;
  int t0 = rw >> 4;                      // this wave's first row-tile index
  f32x4 acc[8];
  #pragma unroll
  for (int i=0;i<8;i++) acc[i] = (f32x4){0.f,0.f,0.f,0.f};
  for (int kc = 0; kc < 4; kc++){
    __syncthreads();
    #pragma unroll
    for (int i=0;i<2;i++){
      if (i*32 + wid*8 < vrows){         // wave-uniform: stage only valid rows
        int cid = i*256 + tid, row = cid >> 3, c8 = cid & 7;
        gl2lds16(xn + (size_t)(row0 + row)*DDIM + kc*64 + ((c8 ^ (row&7))<<3), As + cid*8);
      }
    }
    #pragma unroll
    for (int i=0;i<4;i++){
      int cid = i*256 + tid, row = cid >> 3, c8 = cid & 7;
      gl2lds16(Wqkv + (size_t)(col0 + row)*DDIM + kc*64 + ((c8 ^ (row&7))<<3), Bs + cid*8);
    }
    __syncthreads();
    #pragma unroll
    for (int ks=0; ks<2; ks++){
      int sw = ((ks*4 + quad) ^ (m&7)) << 3;
      s16x8 af[2], bf[4];
      #pragma unroll
      for (int mt=0;mt<2;mt++) if (t0 + mt < qtm) af[mt] = *(const s16x8*)(As + (rw + mt*16 + m)*64 + sw);
      #pragma unroll
      for (int nt=0;nt<4;nt++) bf[nt] = *(const s16x8*)(Bs + (cw + nt*16 + m)*64 + sw);
      #pragma unroll
      for (int mt=0;mt<2;mt++) if (t0 + mt < qtm)
        #pragma unroll
        for (int nt=0;nt<4;nt++)
          acc[mt*4+nt] = __builtin_amdgcn_mfma_f32_16x16x32_bf16(af[mt], bf[nt], acc[mt*4+nt], 0,0,0);
    }
  }
  #pragma unroll
  for (int nt=0;nt<4;nt++){
    int cg = col0 + cw + nt*16 + m;
    int mat = cg >> 8, col = cg & 255;
    float bb = qkvb[cg];
    if (mat < 2){
      unsigned short* ob = (mat==0)?qb:kb_;
      #pragma unroll
      for (int mt=0;mt<2;mt++) if (t0 + mt < qtm)
        #pragma unroll
        for (int r=0;r<4;r++){
          int row = row0 + rw + mt*16 + quad*4 + r;
          ob[(size_t)row*DDIM + col] = f2bf(acc[mt*4+nt][r] + bb);
        }
    } else {
      #pragma unroll
      for (int mt=0;mt<2;mt++) if (t0 + mt < qtm){
        int tok0 = rw + mt*16 + quad*4;
        ushort4 p;
        p.x = f2bf(acc[mt*4+nt][0] + bb);
        p.y = f2bf(acc[mt*4+nt][1] + bb);
        p.z = f2bf(acc[mt*4+nt][2] + bb);
        p.w = f2bf(acc[mt*4+nt][3] + bb);
        *(ushort4*)(vt + ((size_t)node*256 + col)*64 + tok0) = p;
      }
    }
  }
}

// ---------------- attention: block=(src,head), 4 waves=q-tiles, all-async dbuf staging ----------------
__global__ __launch_bounds__(256) void attn_kernel(const unsigned short* qb, const unsigned short* kbuf,
                                                   const unsigned short* vtb, const int* lenp,
                                                   const int* startp, const int* degp, const int* elist,
                                                   const int* order, unsigned short* ctxb){
  __shared__ __align__(16) unsigned short Kt[2][4096];
  __shared__ __align__(16) unsigned short Vt[2][4096];
  __shared__ unsigned short P[4096];
  int tid = threadIdx.x;
  int lane = tid & 63, wid = tid >> 6, m = lane & 15, quad = lane >> 4;
  int src = order[blockIdx.x], h = blockIdx.y;
  int ls = lenp[src];
  int qtm = (ls + 15) >> 4;
  int s0 = startp[src], dg = degp[src];
  bool active = wid < qtm;
  unsigned short* Pw = P + wid*1024;

  s16x8 qf0 = {0,0,0,0,0,0,0,0}, qf1 = {0,0,0,0,0,0,0,0};
  if (active){
    const unsigned short* qbase = qb + (size_t)(src*SLEN + wid*16 + m)*DDIM + h*64 + quad*8;
    qf0 = *(const s16x8*)(qbase);
    qf1 = *(const s16x8*)(qbase + 32);
  }
  f32x4 o[4];
  #pragma unroll
  for (int i=0;i<4;i++) o[i] = (f32x4){0.f,0.f,0.f,0.f};

  int dst0 = 0, dst1 = 0, ld0 = 0;
  if (dg > 0){
    dst0 = elist[s0];
    ld0 = lenp[dst0];
    int kch = ((ld0 + 15) >> 4) * 128;
    #pragma unroll
    for (int i=0;i<2;i++){
      int cid = i*256 + tid;
      if (i*256 + wid*64 < kch){
        int row = cid >> 3, c8 = cid & 7;
        gl2lds16(kbuf + (size_t)(dst0*SLEN + row)*DDIM + h*64 + ((c8 ^ (row&7))<<3), Kt[0] + cid*8);
      }
    }
    const unsigned short* vhead = vtb + ((size_t)dst0*256 + h*64)*64;
    #pragma unroll
    for (int i=0;i<2;i++){
      int cid = i*256 + tid, row = cid >> 3, c8 = cid & 7;
      gl2lds16(vhead + row*64 + ((c8 ^ (row&7))<<3), Vt[0] + cid*8);
    }
  }
  if (dg > 1) dst1 = elist[s0 + 1];
  __syncthreads();

  for (int ei=0; ei<dg; ei++){
    int cur = ei & 1, nxt = cur ^ 1;
    int dst2 = (ei+2 < dg) ? elist[s0 + ei + 2] : 0;
    int ld1 = 0;
    if (ei+1 < dg){
      ld1 = lenp[dst1];
      int kch = ((ld1 + 15) >> 4) * 128;
      #pragma unroll
      for (int i=0;i<2;i++){
        int cid = i*256 + tid;
        if (i*256 + wid*64 < kch){
          int row = cid >> 3, c8 = cid & 7;
          gl2lds16(kbuf + (size_t)(dst1*SLEN + row)*DDIM + h*64 + ((c8 ^ (row&7))<<3), Kt[nxt] + cid*8);
        }
      }
      const unsigned short* vhead = vtb + ((size_t)dst1*256 + h*64)*64;
      #pragma unroll
      for (int i=0;i<2;i++){
        int cid = i*256 + tid, row = cid >> 3, c8 = cid & 7;
        gl2lds16(vhead + row*64 + ((c8 ^ (row&7))<<3), Vt[nxt] + cid*8);
      }
    }
    int ktm = (ld0 + 15) >> 4;
    int ks2 = (ktm + 1) >> 1;
    if (active){
      f32x4 acc[4];
      #pragma unroll
      for (int i=0;i<4;i++) acc[i] = (f32x4){0.f,0.f,0.f,0.f};
      #pragma unroll
      for (int kt=0; kt<4; kt++) if (kt < ktm){
        int key = kt*16 + m;
        s16x8 b0 = *(const s16x8*)(Kt[cur] + key*64 + ((quad ^ (m&7))<<3));
        acc[kt] = __builtin_amdgcn_mfma_f32_16x16x32_bf16(qf0, b0, acc[kt], 0,0,0);
        s16x8 b1 = *(const s16x8*)(Kt[cur] + key*64 + (((4 + quad) ^ (m&7))<<3));
        acc[kt] = __builtin_amdgcn_mfma_f32_16x16x32_bf16(qf1, b1, acc[kt], 0,0,0);
      }
      #pragma unroll
      for (int r=0; r<4; r++){
        float x[4];
        #pragma unroll
        for (int kt=0; kt<4; kt++)
          x[kt] = (kt < ktm && kt*16 + m < ld0) ? __expf(acc[kt][r]*0.125f) : 0.f;
        float s = x[0] + x[1] + x[2] + x[3];
        for (int off=1; off<16; off<<=1) s += __shfl_xor(s, off);
        float inv = 1.0f / s;
        int q = quad*4 + r;
        #pragma unroll
        for (int kt=0; kt<4; kt++) if (kt < 2*ks2){
          int key = kt*16 + m;
          Pw[q*64 + (((key>>3)^(q&7))<<3) + (key&7)] = f2bf(x[kt]*inv);
        }
      }
      #pragma unroll
      for (int ks=0; ks<2; ks++) if (ks < ks2){
        s16x8 pa = *(const s16x8*)(Pw + m*64 + ((((ks*4+quad))^(m&7))<<3));
        #pragma unroll
        for (int dt=0; dt<4; dt++){
          int d = dt*16 + m;
          s16x8 vf = *(const s16x8*)(Vt[cur] + d*64 + (((ks*4+quad)^(d&7))<<3));
          o[dt] = __builtin_amdgcn_mfma_f32_16x16x32_bf16(pa, vf, o[dt], 0,0,0);
        }
      }
    }
    dst0 = dst1; ld0 = ld1; dst1 = dst2;
    __syncthreads();
  }
  if (active){
    #pragma unroll
    for (int dt=0; dt<4; dt++){
      int col = h*64 + dt*16 + m;
      #pragma unroll
      for (int r=0; r<4; r++){
        int row = src*SLEN + wid*16 + quad*4 + r;
        ctxb[(size_t)row*DDIM + col] = f2bf(o[dt][r]);
      }
    }
  }
}

// ---------------- output GEMM, mask-aware: valid tiles full path, masked tiles write zeros ----------------
__global__ __launch_bounds__(256) void out_kernel(const unsigned short* ctxb, const unsigned short* Wo_t,
                                                  const float* bo, const float* nf, const float* masks,
                                                  const int* lenp, float* out){
  __shared__ __align__(16) unsigned short As[4096];
  __shared__ __align__(16) unsigned short Bs[8192];
  int tid = threadIdx.x;
  int lane = tid & 63, wid = tid >> 6, m = lane & 15, quad = lane >> 4;
  int row0 = blockIdx.x * 64;
  int node = row0 >> 6;
  int qtm = (lenp[node] + 15) >> 4;
  int vrows = qtm << 4;
  int col0 = blockIdx.y * 128;
  int rw = (wid & 1) * 32, cw = (wid >> 1) * 64;
  int t0 = rw >> 4;
  f32x4 acc[8];
  #pragma unroll
  for (int i=0;i<8;i++) acc[i] = (f32x4){0.f,0.f,0.f,0.f};
  for (int kc = 0; kc < 4; kc++){
    __syncthreads();
    #pragma unroll
    for (int i=0;i<2;i++){
      if (i*32 + wid*8 < vrows){
        int cid = i*256 + tid, row = cid >> 3, c8 = cid & 7;
        gl2lds16(ctxb + (size_t)(row0 + row)*DDIM + kc*64 + ((c8 ^ (row&7))<<3), As + cid*8);
      }
    }
    #pragma unroll
    for (int i=0;i<4;i++){
      int cid = i*256 + tid, row = cid >> 3, c8 = cid & 7;
      gl2lds16(Wo_t + (size_t)(col0 + row)*DDIM + kc*64 + ((c8 ^ (row&7))<<3), Bs + cid*8);
    }
    __syncthreads();
    #pragma unroll
    for (int ks=0; ks<2; ks++){
      int sw = ((ks*4 + quad) ^ (m&7)) << 3;
      s16x8 af[2], bf[4];
      #pragma unroll
      for (int mt=0;mt<2;mt++) if (t0 + mt < qtm) af[mt] = *(const s16x8*)(As + (rw + mt*16 + m)*64 + sw);
      #pragma unroll
      for (int nt=0;nt<4;nt++) bf[nt] = *(const s16x8*)(Bs + (cw + nt*16 + m)*64 + sw);
      #pragma unroll
      for (int mt=0;mt<2;mt++) if (t0 + mt < qtm)
        #pragma unroll
        for (int nt=0;nt<4;nt++)
          acc[mt*4+nt] = __builtin_amdgcn_mfma_f32_16x16x32_bf16(af[mt], bf[nt], acc[mt*4+nt], 0,0,0);
    }
  }
  #pragma unroll
  for (int nt=0;nt<4;nt++){
    int col = col0 + cw + nt*16 + m;
    float bb = bo[col];
    #pragma unroll
    for (int mt=0;mt<2;mt++){
      if (t0 + mt < qtm){
        #pragma unroll
        for (int r=0;r<4;r++){
          int row = row0 + rw + mt*16 + quad*4 + r;
          float v = acc[mt*4+nt][r] + bb + nf[(size_t)row*DDIM + col];
          out[(size_t)row*DDIM + col] = v * masks[row];
        }
      } else {
        #pragma unroll
        for (int r=0;r<4;r++){
          int row = row0 + rw + mt*16 + quad*4 + r;
          out[(size_t)row*DDIM + col] = 0.f;
        }
      }
    }
  }
}

extern "C" void kernel_launch(void* const* d_in, const int* in_sizes, int n_in,
                              void* d_out, int out_size, void* d_ws, size_t ws_size,
                              hipStream_t stream){
  const float* nf    = (const float*)d_in[0];
  const float* masks = (const float*)d_in[1];
  const float* lnw   = (const float*)d_in[2];
  const float* lnb   = (const float*)d_in[3];
  const float* wq    = (const float*)d_in[4];
  const float* bq    = (const float*)d_in[5];
  const float* wk    = (const float*)d_in[6];
  const float* bk    = (const float*)d_in[7];
  const float* wv    = (const float*)d_in[8];
  const float* bv    = (const float*)d_in[9];
  const float* wo    = (const float*)d_in[10];
  const float* bo    = (const float*)d_in[11];
  const int*   eidx  = (const int*)d_in[13];
  float* out = (float*)d_out;

  char* ws = (char*)d_ws;
  const size_t B = (size_t)ROWS * DDIM * 2;
  unsigned short* xn   = (unsigned short*)(ws);
  unsigned short* qb   = (unsigned short*)(ws + B);
  unsigned short* kb   = (unsigned short*)(ws + 2*B);
  unsigned short* vt   = (unsigned short*)(ws + 3*B);   // V transposed: [node][col 256][token 64]
  unsigned short* ctxb = (unsigned short*)(ws + 4*B);
  char* wp = ws + 5*B;
  unsigned short* Wqkv = (unsigned short*)(wp);
  unsigned short* Wo_t = (unsigned short*)(wp + 393216);
  float* qkvb         = (float*)(wp + 524288);
  char* ip = wp + 528384;
  int* startp = (int*)(ip);
  int* lenp   = (int*)(ip + 4096);
  int* order  = (int*)(ip + 8192);
  int* degp   = (int*)(ip + 12288);
  int* elist  = (int*)(ip + 16384);

  setup_kernel<<<17668, 256, 0, stream>>>(nf, lnw, lnb, wq, wk, wv, wo, bq, bk, bv,
                                          masks, xn, Wqkv, Wo_t, qkvb, lenp);
  csr_kernel<<<1, 1024, 0, stream>>>(eidx, startp, order, degp, elist);
  qkv_kernel<<<dim3(ROWS/64, 6), 256, 0, stream>>>(xn, Wqkv, qkvb, lenp, qb, kb, vt);
  attn_kernel<<<dim3(NNODE, 4), 256, 0, stream>>>(qb, kb, vt, lenp, startp, degp, elist, order, ctxb);
  out_kernel<<<dim3(ROWS/64, 2), 256, 0, stream>>>(ctxb, Wo_t, bo, nf, masks, lenp, out);
}